// Round 8
// baseline (332.922 us; speedup 1.0000x reference)
//
#include <hip/hip_runtime.h>

#define NB 256
#define NT 512
#define NI 64
#define NH 256
#define NO 16

typedef __attribute__((ext_vector_type(8))) short short8;
typedef __attribute__((ext_vector_type(8))) __bf16 bf16x8;
typedef __attribute__((ext_vector_type(2))) float f32x2;
typedef __attribute__((ext_vector_type(4))) float f32x4;
typedef __attribute__((ext_vector_type(4))) int int4v;
typedef __attribute__((ext_vector_type(8))) int int8v;

__device__ __forceinline__ unsigned short f2bf(float f) {
  unsigned u = __builtin_bit_cast(unsigned, f);
  u += 0x7fffu + ((u >> 16) & 1u);          // round-to-nearest-even
  return (unsigned short)(u >> 16);
}

__device__ __forceinline__ f32x4 mfma16(short8 a, short8 b, f32x4 c) {
  return __builtin_amdgcn_mfma_f32_16x16x32_bf16(
      __builtin_bit_cast(bf16x8, a), __builtin_bit_cast(bf16x8, b), c, 0, 0, 0);
}

// MX fp4 K=128 MFMA; block scales pinned to 1.0 (E8M0=127 in every byte).
// cbsz=4 / blgp=4 -> FP4 (E2M1) both operands; fp4 uses low 4 regs of each.
__device__ __forceinline__ f32x4 mfma_fp4(int8v a, int8v b, f32x4 c) {
  return __builtin_amdgcn_mfma_scale_f32_16x16x128_f8f6f4(
      a, b, c, 4, 4, 0, 0x7f7f7f7f, 0, 0x7f7f7f7f);
}

// nearest e2m1 code for v in [-6,6]; codes 0..7 = {0,.5,1,1.5,2,3,4,6}, bit3=sign
__device__ __forceinline__ int fp4s(float v) {
  const float m = fabsf(v);
  int c;
  if (m < 1.75f)      c = (int)(m * 2.f + 0.5f);
  else if (m < 2.5f)  c = 4;
  else if (m < 3.5f)  c = 5;
  else if (m < 5.0f)  c = 6;
  else                c = 7;
  return c | (v < 0.f ? 8 : 0);
}

__device__ __forceinline__ short8 pack8v(f32x4 lo, f32x4 hi) {
  short8 r;
#pragma unroll
  for (int i = 0; i < 4; ++i) {
    r[i]     = (short)f2bf(lo[i]);
    r[i + 4] = (short)f2bf(hi[i]);
  }
  return r;
}

__device__ __forceinline__ short8 pack8(const float* __restrict__ p) {
  return pack8v(*reinterpret_cast<const f32x4*>(p),
                *reinterpret_cast<const f32x4*>(p + 4));
}

// LDS-only barrier: drain DS ops, sync; global stores/loads stay in flight.
__device__ __forceinline__ void step_barrier() {
  asm volatile("s_waitcnt lgkmcnt(0)" ::: "memory");
  __builtin_amdgcn_s_barrier();
  asm volatile("" ::: "memory");
}

// One block per batch. 512 threads = 8 waves (2/SIMD).
// h2h via MX-fp4 K=128: A = broadcast h (fp4 x6), B = per-row-scaled Wh (fp4).
// EVEN/ODD j-map: wave w, tile jt, col ll <-> W row j = w*32 + 2*ll + jt, so
// each lane's two outputs are adjacent units -> local nibble pack, float2 out.
__global__ __launch_bounds__(512, 2)
void rnn_fused(const float* __restrict__ x,  const float* __restrict__ Wi,
               const float* __restrict__ bi, const float* __restrict__ Wh,
               const float* __restrict__ bh, const float* __restrict__ Wo,
               const float* __restrict__ bo, const float* __restrict__ h0,
               float* __restrict__ dout)
{
  const int b   = blockIdx.x;
  const int tid = threadIdx.x;
  const int w   = tid >> 6;   // wave 0..7
  const int l   = tid & 63;   // lane
  const int lg  = l >> 4;     // 16-lane group
  const int ll  = l & 15;     // index within tile

  __shared__ __align__(16) unsigned char  hq4[2][128];      // fp4 h, nibble-packed
  __shared__ __align__(16) unsigned short rnnwin[16 * NH];  // 8 KB bf16 ring
  __shared__ __align__(16) float          xi_lds[NH][20];   // [j][t(16)+pad4]

  float* outp = dout;                              // [B,T,O]
  float* hidp = dout + (size_t)NB * NT * NO;       // [B,H]
  float* rnnp = hidp + (size_t)NB * NH;            // [B,T,H]

  const f32x4 cz  = {0.f, 0.f, 0.f, 0.f};
  const int4v i4z = {0, 0, 0, 0};

  // ---- Wh -> fp4 B-fragments, per-row scale 6/m; row j = w*32 + 2*ll + jt,
  //      k = kc*128 + lg*32 + e (nibble e&1 of byte (kc*64 + lg*16 + e/2)) ----
  int8v wq8[2][2];
  float dq[2];
#pragma unroll
  for (int jt = 0; jt < 2; ++jt) {
    const int j = w * 32 + 2 * ll + jt;
    const float* wr = Wh + (size_t)j * NH;
    float m = 0.f;
#pragma unroll
    for (int kc = 0; kc < 2; ++kc)
#pragma unroll
      for (int e4 = 0; e4 < 8; ++e4) {
        f32x4 v = *reinterpret_cast<const f32x4*>(wr + kc * 128 + lg * 32 + e4 * 4);
#pragma unroll
        for (int i = 0; i < 4; ++i) m = fmaxf(m, fabsf(v[i]));
      }
    m = fmaxf(m, __shfl_xor(m, 16));
    m = fmaxf(m, __shfl_xor(m, 32));
    const float s = (m > 0.f) ? 6.f / m : 0.f;
    dq[jt] = m * (1.f / 36.f);
#pragma unroll
    for (int kc = 0; kc < 2; ++kc) {
      unsigned u[4] = {0u, 0u, 0u, 0u};
#pragma unroll
      for (int e = 0; e < 32; ++e) {
        const int code = fp4s(wr[kc * 128 + lg * 32 + e] * s);
        u[e >> 3] |= ((unsigned)code) << (4 * (e & 7));
      }
      int4v t4; t4[0] = (int)u[0]; t4[1] = (int)u[1]; t4[2] = (int)u[2]; t4[3] = (int)u[3];
      wq8[jt][kc] = __builtin_shufflevector(t4, i4z, 0, 1, 2, 3, 4, 5, 6, 7);
    }
  }

  // ---- bf16 i2h weights (persistent, 16 VGPR); out-proj loaded per window ----
  short8 wif[2][2];
#pragma unroll
  for (int jt = 0; jt < 2; ++jt) {
    const int j = w * 32 + jt * 16 + ll;
#pragma unroll
    for (int kx = 0; kx < 2; ++kx)
      wif[jt][kx] = pack8(Wi + (size_t)j * NI + kx * 32 + lg * 8);
  }

  const int je = w * 32 + 2 * ll;      // even j this lane owns
  float breg0 = bi[je]     + bh[je];
  float breg1 = bi[je + 1] + bh[je + 1];
  const float bout = bo[ll];

  float h_reg0 = h0[je];
  float h_reg1 = h0[je + 1];

  // ---- init hq4[0] from h0 (2 units per byte) ----
  if (tid < 128) {
    const int q0 = fp4s(fminf(fmaxf(h0[2 * tid],     -1.f), 1.f) * 6.f);
    const int q1 = fp4s(fminf(fmaxf(h0[2 * tid + 1], -1.f), 1.f) * 6.f);
    hq4[0][tid] = (unsigned char)(q0 | (q1 << 4));
  }

  // ---- x prefetch (one window ahead): lane row ll, 16 f32 ----
  const float* xrow = x + (size_t)b * NT * NI + (size_t)ll * NI + lg * 8;
  f32x4 xpre[4];
  xpre[0] = *reinterpret_cast<const f32x4*>(xrow);
  xpre[1] = *reinterpret_cast<const f32x4*>(xrow + 4);
  xpre[2] = *reinterpret_cast<const f32x4*>(xrow + 32);
  xpre[3] = *reinterpret_cast<const f32x4*>(xrow + 36);

  __syncthreads();

  auto outproj = [&](int tbase) {    // out[tbase-16 .. tbase-1] from rnnwin
    f32x4 oacc = cz;
#pragma unroll
    for (int kt = 0; kt < 8; ++kt) {
      short8 wo = pack8(Wo + (size_t)ll * NH + kt * 32 + lg * 8);
      const char* ap = (const char*)rnnwin + ll * 512 +
                       ((kt * 64 + lg * 16) ^ (ll << 4));
      short8 af = *reinterpret_cast<const short8*>(ap);
      oacc = mfma16(af, wo, oacc);
    }
#pragma unroll
    for (int r = 0; r < 4; ++r) {
      const int tp = lg * 4 + r;
      outp[((size_t)b * NT + tbase - 16 + tp) * NO + ll] = oacc[r] + bout;
    }
  };

#pragma unroll 1
  for (int t0 = 0; t0 < NT; t0 += 16) {
    // ---- window boundary ----
    if (t0 > 0 && w == 0) outproj(t0);
    {
      short8 xf0 = pack8v(xpre[0], xpre[1]);
      short8 xf1 = pack8v(xpre[2], xpre[3]);
#pragma unroll
      for (int jt = 0; jt < 2; ++jt) {
        f32x4 acc = mfma16(xf0, wif[jt][0], cz);
        acc = mfma16(xf1, wif[jt][1], acc);
        const int j = w * 32 + jt * 16 + ll;
        *(f32x4*)&xi_lds[j][lg * 4] = acc;   // rows r -> t = lg*4 + r
      }
    }
    if (t0 + 16 < NT) {
      const float* xp = x + (size_t)b * NT * NI + (size_t)(t0 + 16 + ll) * NI + lg * 8;
      xpre[0] = *reinterpret_cast<const f32x4*>(xp);
      xpre[1] = *reinterpret_cast<const f32x4*>(xp + 4);
      xpre[2] = *reinterpret_cast<const f32x4*>(xp + 32);
      xpre[3] = *reinterpret_cast<const f32x4*>(xp + 36);
    }
    step_barrier();

#pragma unroll 1
    for (int q4 = 0; q4 < 4; ++q4) {
      const int tb = t0 + q4 * 4;
      f32x4 xiA = *(const f32x4*)&xi_lds[je][q4 * 4];
      f32x4 xiB = *(const f32x4*)&xi_lds[je + 1][q4 * 4];

#define STEP(TT, SUB)                                                          \
      {                                                                        \
        const int t    = (TT);                                                 \
        const int trow = t & 15;                                               \
        const int p    = t & 1;                                                \
        int4v h4a = *(const int4v*)&hq4[p][lg * 16];                           \
        int4v h4b = *(const int4v*)&hq4[p][64 + lg * 16];                      \
        int8v A0 = __builtin_shufflevector(h4a, i4z, 0, 1, 2, 3, 4, 5, 6, 7);  \
        int8v A1 = __builtin_shufflevector(h4b, i4z, 0, 1, 2, 3, 4, 5, 6, 7);  \
        const float hxi0 = h_reg0 + xiA[SUB] + breg0;                          \
        const float hxi1 = h_reg1 + xiB[SUB] + breg1;                          \
        f32x4 acc0 = mfma_fp4(A0, wq8[0][0], cz);                              \
        f32x4 acc1 = mfma_fp4(A0, wq8[1][0], cz);                              \
        acc0 = mfma_fp4(A1, wq8[0][1], acc0);                                  \
        acc1 = mfma_fp4(A1, wq8[1][1], acc1);                                  \
        const float a0 = fminf(fmaxf(fmaf(acc0[0], dq[0], hxi0), 0.f), 1.f);   \
        const float a1 = fminf(fmaxf(fmaf(acc1[0], dq[1], hxi1), 0.f), 1.f);   \
        h_reg0 = a0; h_reg1 = a1;                                              \
        if (lg == 0) {                                                         \
          hq4[p ^ 1][w * 16 + ll] =                                            \
              (unsigned char)(fp4s(a0 * 6.f) | (fp4s(a1 * 6.f) << 4));         \
          *(unsigned*)((char*)rnnwin + trow * 512 +                            \
                       ((4 * (w * 16 + ll)) ^ (trow << 4))) =                  \
              (unsigned)f2bf(a0) | ((unsigned)f2bf(a1) << 16);                 \
          f32x2 o2; o2[0] = a0; o2[1] = a1;                                    \
          *(f32x2*)(rnnp + ((size_t)b * NT + t) * NH + je) = o2;               \
        }                                                                      \
        step_barrier();                                                        \
      }

      STEP(tb + 0, 0)
      STEP(tb + 1, 1)
      STEP(tb + 2, 2)
      STEP(tb + 3, 3)
#undef STEP
    }
  }

  // ---- epilogue: final window out-proj + hidden ----
  if (w == 0) outproj(NT);
  if (lg == 0) {
    f32x2 h2; h2[0] = h_reg0; h2[1] = h_reg1;
    *(f32x2*)(hidp + (size_t)b * NH + je) = h2;
  }
}

extern "C" void kernel_launch(void* const* d_in, const int* in_sizes, int n_in,
                              void* d_out, int out_size, void* d_ws, size_t ws_size,
                              hipStream_t stream) {
  const float* x  = (const float*)d_in[0];
  const float* Wi = (const float*)d_in[1];
  const float* bi = (const float*)d_in[2];
  const float* Wh = (const float*)d_in[3];
  const float* bh = (const float*)d_in[4];
  const float* Wo = (const float*)d_in[5];
  const float* bo = (const float*)d_in[6];
  const float* h0 = (const float*)d_in[7];
  rnn_fused<<<dim3(NB), dim3(512), 0, stream>>>(x, Wi, bi, Wh, bh, Wo, bo, h0,
                                                (float*)d_out);
}

// Round 9
// 206.000 us; speedup vs baseline: 1.6161x; 1.6161x over previous
//
#include <hip/hip_runtime.h>

#define NB 256
#define NT 512
#define NI 64
#define NH 256
#define NO 16

typedef __attribute__((ext_vector_type(8))) short short8;
typedef __attribute__((ext_vector_type(8))) __bf16 bf16x8;
typedef __attribute__((ext_vector_type(2))) float f32x2;
typedef __attribute__((ext_vector_type(4))) float f32x4;
typedef __attribute__((ext_vector_type(4))) int int4v;
typedef __attribute__((ext_vector_type(8))) int int8v;

#define XI_STRIDE 260   // floats; bank-spread + alignment derived (see xi notes)

__device__ __forceinline__ unsigned short f2bf(float f) {
  unsigned u = __builtin_bit_cast(unsigned, f);
  u += 0x7fffu + ((u >> 16) & 1u);          // round-to-nearest-even
  return (unsigned short)(u >> 16);
}

__device__ __forceinline__ f32x4 mfma16(short8 a, short8 b, f32x4 c) {
  return __builtin_amdgcn_mfma_f32_16x16x32_bf16(
      __builtin_bit_cast(bf16x8, a), __builtin_bit_cast(bf16x8, b), c, 0, 0, 0);
}

// fp8(e4m3) K=128 MFMA via f8f6f4, block scales pinned to 1.0.
// cbsz=0 / blgp=0 -> FP8 both operands; full 8-reg (32B/lane) operands.
__device__ __forceinline__ f32x4 mfma_fp8(int8v a, int8v b, f32x4 c) {
  return __builtin_amdgcn_mfma_scale_f32_16x16x128_f8f6f4(
      a, b, c, 0, 0, 0, 0x7f7f7f7f, 0, 0x7f7f7f7f);
}

__device__ __forceinline__ short8 pack8v(f32x4 lo, f32x4 hi) {
  short8 r;
#pragma unroll
  for (int i = 0; i < 4; ++i) {
    r[i]     = (short)f2bf(lo[i]);
    r[i + 4] = (short)f2bf(hi[i]);
  }
  return r;
}

__device__ __forceinline__ short8 pack8(const float* __restrict__ p) {
  return pack8v(*reinterpret_cast<const f32x4*>(p),
                *reinterpret_cast<const f32x4*>(p + 4));
}

// LDS-only barrier: drain DS ops, sync; global stores/loads stay in flight.
__device__ __forceinline__ void step_barrier() {
  asm volatile("s_waitcnt lgkmcnt(0)" ::: "memory");
  __builtin_amdgcn_s_barrier();
  asm volatile("" ::: "memory");
}

// One block per batch. 512 threads = 8 waves (2/SIMD).
// h2h via fp8 K=128 MFMA: A = broadcast h (e4m3, linear byte buffer),
// B = per-row-scaled Wh (e4m3). Even/odd j-map: lane ll owns j = w*32+2*ll
// (+1), so h/rnnwin/rnn_out writes pack locally, no shuffles.
__global__ __launch_bounds__(512, 2)
void rnn_fused(const float* __restrict__ x,  const float* __restrict__ Wi,
               const float* __restrict__ bi, const float* __restrict__ Wh,
               const float* __restrict__ bh, const float* __restrict__ Wo,
               const float* __restrict__ bo, const float* __restrict__ h0,
               float* __restrict__ dout)
{
  const int b   = blockIdx.x;
  const int tid = threadIdx.x;
  const int w   = tid >> 6;   // wave 0..7
  const int l   = tid & 63;   // lane
  const int lg  = l >> 4;     // 16-lane group
  const int ll  = l & 15;     // index within tile

  __shared__ __align__(16) unsigned char  hq8[2][256];      // e4m3 h, linear j
  __shared__ __align__(16) unsigned short rnnwin[16 * NH];  // 8 KB bf16 ring
  __shared__ __align__(16) float          xi_t[16 * XI_STRIDE]; // [trow][j]+pad

  float* outp = dout;                              // [B,T,O]
  float* hidp = dout + (size_t)NB * NT * NO;       // [B,H]
  float* rnnp = hidp + (size_t)NB * NH;            // [B,T,H]

  const f32x4 cz = {0.f, 0.f, 0.f, 0.f};

  // ---- Wh -> e4m3 B-fragments, per-row scale 224/m; row j = w*32+2*ll+jt,
  //      k = kc*128 + lg*32 + e (byte e of v[0:7]) ----
  int8v wq8[2][2];
  float dq[2];
#pragma unroll
  for (int jt = 0; jt < 2; ++jt) {
    const int j = w * 32 + 2 * ll + jt;
    const float* wr = Wh + (size_t)j * NH;
    float m = 0.f;
#pragma unroll
    for (int kc = 0; kc < 2; ++kc)
#pragma unroll
      for (int q8 = 0; q8 < 8; ++q8) {
        f32x4 v = *reinterpret_cast<const f32x4*>(wr + kc * 128 + lg * 32 + q8 * 4);
#pragma unroll
        for (int i = 0; i < 4; ++i) m = fmaxf(m, fabsf(v[i]));
      }
    m = fmaxf(m, __shfl_xor(m, 16));
    m = fmaxf(m, __shfl_xor(m, 32));
    const float s = (m > 0.f) ? 224.f / m : 0.f;
    dq[jt] = m * (1.f / 224.f);
#pragma unroll
    for (int kc = 0; kc < 2; ++kc) {
      int8v t8;
#pragma unroll
      for (int q8 = 0; q8 < 8; ++q8) {
        f32x4 v = *reinterpret_cast<const f32x4*>(wr + kc * 128 + lg * 32 + q8 * 4);
        int lo = __builtin_amdgcn_cvt_pk_fp8_f32(v[0] * s, v[1] * s, 0, false);
        t8[q8] = __builtin_amdgcn_cvt_pk_fp8_f32(v[2] * s, v[3] * s, lo, true);
      }
      wq8[jt][kc] = t8;
    }
  }

  // ---- bf16 i2h weights (persistent, 16 VGPR); out-proj loaded per window ----
  short8 wif[2][2];
#pragma unroll
  for (int jt = 0; jt < 2; ++jt) {
    const int j = w * 32 + jt * 16 + ll;
#pragma unroll
    for (int kx = 0; kx < 2; ++kx)
      wif[jt][kx] = pack8(Wi + (size_t)j * NI + kx * 32 + lg * 8);
  }

  const int je = w * 32 + 2 * ll;      // even j this lane owns (+1 = odd)
  const float breg0 = bi[je]     + bh[je];
  const float breg1 = bi[je + 1] + bh[je + 1];
  const float bout = bo[ll];

  float h_reg0 = h0[je];
  float h_reg1 = h0[je + 1];

  // ---- init hq8[0] from h0 ----
  if (tid < 128) {
    int v = __builtin_amdgcn_cvt_pk_fp8_f32(h0[2 * tid], h0[2 * tid + 1], 0, false);
    *(unsigned short*)&hq8[0][2 * tid] = (unsigned short)v;
  }

  // ---- x prefetch (one window ahead): lane row ll, 16 f32 ----
  const float* xrow = x + (size_t)b * NT * NI + (size_t)ll * NI + lg * 8;
  f32x4 xpre[4];
  xpre[0] = *reinterpret_cast<const f32x4*>(xrow);
  xpre[1] = *reinterpret_cast<const f32x4*>(xrow + 4);
  xpre[2] = *reinterpret_cast<const f32x4*>(xrow + 32);
  xpre[3] = *reinterpret_cast<const f32x4*>(xrow + 36);

  __syncthreads();

  auto outproj = [&](int tbase) {    // out[tbase-16 .. tbase-1] from rnnwin
    f32x4 oacc = cz;
#pragma unroll
    for (int kt = 0; kt < 8; ++kt) {
      short8 wo = pack8(Wo + (size_t)ll * NH + kt * 32 + lg * 8);
      const char* ap = (const char*)rnnwin + ll * 512 +
                       ((kt * 64 + lg * 16) ^ (ll << 4));
      short8 af = *reinterpret_cast<const short8*>(ap);
      oacc = mfma16(af, wo, oacc);
    }
#pragma unroll
    for (int r = 0; r < 4; ++r) {
      const int tp = lg * 4 + r;
      outp[((size_t)b * NT + tbase - 16 + tp) * NO + ll] = oacc[r] + bout;
    }
  };

#pragma unroll 1
  for (int t0 = 0; t0 < NT; t0 += 16) {
    // ---- window boundary ----
    if (t0 > 0 && w == 0) outproj(t0);
    {
      short8 xf0 = pack8v(xpre[0], xpre[1]);
      short8 xf1 = pack8v(xpre[2], xpre[3]);
#pragma unroll
      for (int jt = 0; jt < 2; ++jt) {
        f32x4 acc = mfma16(xf0, wif[jt][0], cz);
        acc = mfma16(xf1, wif[jt][1], acc);
        const int j = w * 32 + jt * 16 + ll;
#pragma unroll
        for (int r = 0; r < 4; ++r)
          xi_t[(lg * 4 + r) * XI_STRIDE + j] = acc[r];   // raw (bias in tail)
      }
    }
    if (t0 + 16 < NT) {
      const float* xp = x + (size_t)b * NT * NI + (size_t)(t0 + 16 + ll) * NI + lg * 8;
      xpre[0] = *reinterpret_cast<const f32x4*>(xp);
      xpre[1] = *reinterpret_cast<const f32x4*>(xp + 4);
      xpre[2] = *reinterpret_cast<const f32x4*>(xp + 32);
      xpre[3] = *reinterpret_cast<const f32x4*>(xp + 36);
    }
    step_barrier();

#define STEP(TT)                                                               \
    {                                                                          \
      const int t    = (TT);                                                   \
      const int trow = t & 15;                                                 \
      const int p    = t & 1;                                                  \
      const unsigned char* hb = hq8[p];                                        \
      int8v A0, A1;                                                            \
      *(int4v*)&A0       = *(const int4v*)(hb + lg * 32);                      \
      *((int4v*)&A0 + 1) = *(const int4v*)(hb + lg * 32 + 16);                 \
      *(int4v*)&A1       = *(const int4v*)(hb + 128 + lg * 32);                \
      *((int4v*)&A1 + 1) = *(const int4v*)(hb + 128 + lg * 32 + 16);           \
      f32x2 xi2 = *(const f32x2*)&xi_t[trow * XI_STRIDE + je];                 \
      const float hxi0 = h_reg0 + xi2[0] + breg0;                              \
      const float hxi1 = h_reg1 + xi2[1] + breg1;                              \
      f32x4 acc0 = mfma_fp8(A0, wq8[0][0], cz);                                \
      f32x4 acc1 = mfma_fp8(A0, wq8[1][0], cz);                                \
      acc0 = mfma_fp8(A1, wq8[0][1], acc0);                                    \
      acc1 = mfma_fp8(A1, wq8[1][1], acc1);                                    \
      const float a0 = fminf(fmaxf(fmaf(acc0[0], dq[0], hxi0), 0.f), 1.f);     \
      const float a1 = fminf(fmaxf(fmaf(acc1[0], dq[1], hxi1), 0.f), 1.f);     \
      h_reg0 = a0; h_reg1 = a1;                                                \
      if (lg == 0) {                                                           \
        int hv = __builtin_amdgcn_cvt_pk_fp8_f32(a0, a1, 0, false);            \
        *(unsigned short*)&hq8[p ^ 1][je] = (unsigned short)hv;                \
        *(unsigned*)((char*)rnnwin + trow * 512 +                              \
                     ((4 * (w * 16 + ll)) ^ (trow << 4))) =                    \
            (unsigned)f2bf(a0) | ((unsigned)f2bf(a1) << 16);                   \
        f32x2 o2; o2[0] = a0; o2[1] = a1;                                      \
        *(f32x2*)(rnnp + ((size_t)b * NT + t) * NH + je) = o2;                 \
      }                                                                        \
      step_barrier();                                                          \
    }

#pragma unroll 1
    for (int tt = 0; tt < 16; tt += 2) {
      STEP(t0 + tt)
      STEP(t0 + tt + 1)
    }
#undef STEP
  }

  // ---- epilogue: final window out-proj + hidden ----
  if (w == 0) outproj(NT);
  if (lg == 0) {
    f32x2 h2; h2[0] = h_reg0; h2[1] = h_reg1;
    *(f32x2*)(hidp + (size_t)b * NH + je) = h2;
  }
}

extern "C" void kernel_launch(void* const* d_in, const int* in_sizes, int n_in,
                              void* d_out, int out_size, void* d_ws, size_t ws_size,
                              hipStream_t stream) {
  const float* x  = (const float*)d_in[0];
  const float* Wi = (const float*)d_in[1];
  const float* bi = (const float*)d_in[2];
  const float* Wh = (const float*)d_in[3];
  const float* bh = (const float*)d_in[4];
  const float* Wo = (const float*)d_in[5];
  const float* bo = (const float*)d_in[6];
  const float* h0 = (const float*)d_in[7];
  rnn_fused<<<dim3(NB), dim3(512), 0, stream>>>(x, Wi, bi, Wh, bh, Wo, bo, h0,
                                                (float*)d_out);
}